// Round 6
// baseline (183.125 us; speedup 1.0000x reference)
//
#include <hip/hip_runtime.h>

typedef unsigned short u16;
typedef unsigned int   u32;
typedef __bf16 bf16x8 __attribute__((ext_vector_type(8)));
typedef float  f32x4  __attribute__((ext_vector_type(4)));
typedef u16    u16x8  __attribute__((ext_vector_type(8)));
typedef u16    u16x4  __attribute__((ext_vector_type(4)));

__device__ __forceinline__ float b2f(u16 h) {
  return __builtin_bit_cast(float, ((u32)h) << 16);
}
__device__ __forceinline__ u16 f2b(float f) {
  u32 u = __builtin_bit_cast(u32, f);
  u32 r = u + 0x7FFFu + ((u >> 16) & 1u);
  return (u16)(r >> 16);
}

#define GLD_AS1(p) ((const __attribute__((address_space(1))) void*)(p))
#define LDS_AS3(p) ((__attribute__((address_space(3))) void*)(p))

// ---------------------------------------------------------------------------
// GEMM1 + fused softmax + transposed k/v stores. (unchanged)
// ---------------------------------------------------------------------------
__global__ void gemm_qkv_kernel(const u16* __restrict__ A, const u16* __restrict__ Bt,
                                u16* __restrict__ qb, u16* __restrict__ kT,
                                u16* __restrict__ vT) {
  const int K = 512;
  __shared__ u16 smem[2 * 64 * 72];  // staging (16 KB) U transpose scratch
  u16* As = smem;
  u16* Bs = smem + 128 * 32;
  const int id = blockIdx.x;
  const int tn = id >> 7;
  const int tm = (id & 7) * 16 + ((id >> 3) & 15);
  const int tileN = tn * 128;
  const int tileM = tm * 128;
  const int t = threadIdx.x;
  const int lane = t & 63;
  const int wave = t >> 6;
  const int mbase = (wave >> 1) * 64;
  const int nbase = (wave & 1) * 64;
  const int fm = lane & 15;
  const int kg = lane >> 4;

  f32x4 acc[4][4];
#pragma unroll
  for (int i = 0; i < 4; ++i)
#pragma unroll
    for (int j = 0; j < 4; ++j) acc[i][j] = (f32x4){0.f, 0.f, 0.f, 0.f};

  for (int k0 = 0; k0 < K; k0 += 32) {
#pragma unroll
    for (int p = 0; p < 2; ++p) {
      int c = p * 256 + t;
      int r = c >> 2;
      int g = (c & 3) ^ ((r >> 1) & 3);
      const u16* ga = A + (size_t)(tileM + r) * K + (k0 + g * 8);
      __builtin_amdgcn_global_load_lds(GLD_AS1(ga), LDS_AS3(As + c * 8), 16, 0, 0);
      const u16* gb = Bt + (size_t)(tileN + r) * K + (k0 + g * 8);
      __builtin_amdgcn_global_load_lds(GLD_AS1(gb), LDS_AS3(Bs + c * 8), 16, 0, 0);
    }
    __syncthreads();

    bf16x8 af[4], bfr[4];
#pragma unroll
    for (int mi = 0; mi < 4; ++mi) {
      int m = mbase + mi * 16 + fm;
      int sg = kg ^ ((m >> 1) & 3);
      af[mi] = *(const bf16x8*)(As + m * 32 + sg * 8);
    }
#pragma unroll
    for (int ni = 0; ni < 4; ++ni) {
      int n = nbase + ni * 16 + fm;
      int sg = kg ^ ((n >> 1) & 3);
      bfr[ni] = *(const bf16x8*)(Bs + n * 32 + sg * 8);
    }
#pragma unroll
    for (int mi = 0; mi < 4; ++mi)
#pragma unroll
      for (int ni = 0; ni < 4; ++ni)
        acc[mi][ni] = __builtin_amdgcn_mfma_f32_16x16x32_bf16(af[mi], bfr[ni],
                                                              acc[mi][ni], 0, 0, 0);
    __syncthreads();
  }

  const int rq = lane >> 4;
  const int region = tn >> 2;  // 0 q, 1 k, 2 v

  float inv[4][4];
  if (region <= 1) {
#pragma unroll
    for (int mi = 0; mi < 4; ++mi)
#pragma unroll
      for (int ni = 0; ni < 4; ++ni)
#pragma unroll
        for (int reg = 0; reg < 4; ++reg)
          acc[mi][ni][reg] = __expf(acc[mi][ni][reg]);
#pragma unroll
    for (int mi = 0; mi < 4; ++mi)
#pragma unroll
      for (int reg = 0; reg < 4; ++reg) {
        float s = acc[mi][0][reg] + acc[mi][1][reg] + acc[mi][2][reg] + acc[mi][3][reg];
        s += __shfl_xor(s, 1);
        s += __shfl_xor(s, 2);
        s += __shfl_xor(s, 4);
        s += __shfl_xor(s, 8);
        inv[mi][reg] = 1.f / s;
      }
  } else {
#pragma unroll
    for (int mi = 0; mi < 4; ++mi)
#pragma unroll
      for (int reg = 0; reg < 4; ++reg) inv[mi][reg] = 1.f;
  }

  if (region == 0) {
#pragma unroll
    for (int mi = 0; mi < 4; ++mi)
#pragma unroll
      for (int ni = 0; ni < 4; ++ni)
#pragma unroll
        for (int reg = 0; reg < 4; ++reg) {
          int gr = tileM + mbase + mi * 16 + rq * 4 + reg;
          int gc = tileN + nbase + ni * 16 + fm;
          qb[(size_t)gr * 512 + gc] = f2b(acc[mi][ni][reg] * inv[mi][reg]);
        }
  }

  u16* scw = smem + (wave & 1) * (64 * 72);
  u16* base = (region == 1) ? kT : vT;
  const int hd = tileN + nbase - ((region == 1) ? 512 : 1024);
  const int gr0 = tileM + mbase;
  const int bh = (gr0 >> 12) * 8 + (hd >> 6);
  const int n0 = gr0 & 4095;

  auto transpose_store = [&]() {
#pragma unroll
    for (int mi = 0; mi < 4; ++mi)
#pragma unroll
      for (int ni = 0; ni < 4; ++ni) {
        u16x4 o;
#pragma unroll
        for (int reg = 0; reg < 4; ++reg)
          o[reg] = f2b(acc[mi][ni][reg] * inv[mi][reg]);
        *(u16x4*)(scw + (ni * 16 + fm) * 72 + mi * 16 + rq * 4) = o;
      }
#pragma unroll
    for (int i = 0; i < 8; ++i) {
      int row = i * 8 + (lane >> 3);
      int seg = lane & 7;
      u16x8 val = *(const u16x8*)(scw + row * 72 + seg * 8);
      *(u16x8*)(base + ((size_t)bh * 64 + row) * 4096 + n0 + seg * 8) = val;
    }
  };

  if (region != 0 && wave < 2) transpose_store();
  __syncthreads();
  if (region != 0 && wave >= 2) transpose_store();
}

// ---------------------------------------------------------------------------
// prep_all: [0,4096) cast x; [4096,4288) Wt tiles; [4288,4352) Wot tiles.
// ---------------------------------------------------------------------------
__global__ void prep_all_kernel(const float* __restrict__ x, const float* __restrict__ Wq,
                                const float* __restrict__ Wk, const float* __restrict__ Wv,
                                const float* __restrict__ Wo, u16* __restrict__ xb,
                                u16* __restrict__ Wt, u16* __restrict__ Wot) {
  __shared__ u16 tr[64 * 72];
  const int id = blockIdx.x;
  const int t = threadIdx.x;

  if (id < 4096) {
    int i = (id * 256 + t) * 8;
    float4 a = *(const float4*)(x + i);
    float4 b = *(const float4*)(x + i + 4);
    u16x8 o;
    o[0] = f2b(a.x); o[1] = f2b(a.y); o[2] = f2b(a.z); o[3] = f2b(a.w);
    o[4] = f2b(b.x); o[5] = f2b(b.y); o[6] = f2b(b.z); o[7] = f2b(b.w);
    *(u16x8*)(xb + i) = o;
    return;
  }
  const float* W;
  u16* dst;
  int n0, k0;
  if (id < 4288) {
    int tile = id - 4096;
    n0 = (tile >> 3) * 64;
    k0 = (tile & 7) * 64;
    W = (n0 < 512) ? Wq : ((n0 < 1024) ? Wk : Wv);
    dst = Wt;
  } else {
    int tile = id - 4288;
    n0 = (tile >> 3) * 64;
    k0 = (tile & 7) * 64;
    W = Wo;
    dst = Wot;
  }
  int cin = (n0 & 511);
  int c = t & 63;
  int r0 = t >> 6;
#pragma unroll
  for (int i = 0; i < 16; ++i) {
    int r = r0 * 16 + i;
    tr[c * 72 + r] = f2b(W[(size_t)(k0 + r) * 512 + cin + c]);
  }
  __syncthreads();
#pragma unroll
  for (int j = 0; j < 2; ++j) {
    int idx = j * 256 + t;
    int row = idx >> 3;
    int seg = idx & 7;
    u16x8 val = *(const u16x8*)(tr + row * 72 + seg * 8);
    *(u16x8*)(dst + (size_t)(n0 + row) * 512 + k0 + seg * 8) = val;
  }
}

// ---------------------------------------------------------------------------
// context partials: ctxp[s][bh][e][d] (non-atomic; reduced by ctx_reduce).
// ---------------------------------------------------------------------------
__global__ void context_kernel(const u16* __restrict__ kT, const u16* __restrict__ vT,
                               float* __restrict__ ctxp) {
  __shared__ u16 ks_lds[64 * 32];
  __shared__ u16 vs_lds[64 * 32];
  const int bh = blockIdx.x;
  const int s = blockIdx.y;
  const int t = threadIdx.x;
  const int lane = t & 63;
  const int wave = t >> 6;
  const int fm = lane & 15;
  const int kg = lane >> 4;

  const u16* kbase = kT + (size_t)bh * 64 * 4096;
  const u16* vbase = vT + (size_t)bh * 64 * 4096;
  const int r = t >> 2;
  const int slot = t & 3;
  const int g = slot ^ ((r >> 1) & 3);
  const size_t goff = (size_t)r * 4096 + s * 256 + g * 8;

  f32x4 acc[4];
#pragma unroll
  for (int i = 0; i < 4; ++i) acc[i] = (f32x4){0.f, 0.f, 0.f, 0.f};

  for (int ki = 0; ki < 8; ++ki) {
    __builtin_amdgcn_global_load_lds(GLD_AS1(vbase + goff + ki * 32),
                                     LDS_AS3(vs_lds + t * 8), 16, 0, 0);
    __builtin_amdgcn_global_load_lds(GLD_AS1(kbase + goff + ki * 32),
                                     LDS_AS3(ks_lds + t * 8), 16, 0, 0);
    __syncthreads();
    int e = wave * 16 + fm;
    bf16x8 af = *(const bf16x8*)(vs_lds + e * 32 + (kg ^ ((e >> 1) & 3)) * 8);
#pragma unroll
    for (int dt = 0; dt < 4; ++dt) {
      int d = dt * 16 + fm;
      bf16x8 bfr = *(const bf16x8*)(ks_lds + d * 32 + (kg ^ ((d >> 1) & 3)) * 8);
      acc[dt] = __builtin_amdgcn_mfma_f32_16x16x32_bf16(af, bfr, acc[dt], 0, 0, 0);
    }
    __syncthreads();
  }

  const int rq = lane >> 4;
  float* cp = ctxp + ((size_t)s * 32 + bh) * 4096;
#pragma unroll
  for (int dt = 0; dt < 4; ++dt)
#pragma unroll
    for (int reg = 0; reg < 4; ++reg)
      cp[(wave * 16 + rq * 4 + reg) * 64 + dt * 16 + fm] = acc[dt][reg];
}

// ---------------------------------------------------------------------------
// ctx_reduce: ctxb[bh][e][d] (bf16) = sum_s ctxp[s][bh][e][d]
// ---------------------------------------------------------------------------
__global__ void ctx_reduce_kernel(const float* __restrict__ ctxp, u16* __restrict__ ctxb) {
  const int bh = blockIdx.x;
  const int t = threadIdx.x;
#pragma unroll
  for (int it = 0; it < 4; ++it) {
    int idx = it * 1024 + t * 4;
    f32x4 s = (f32x4){0.f, 0.f, 0.f, 0.f};
#pragma unroll
    for (int p = 0; p < 16; ++p)
      s += *(const f32x4*)(ctxp + ((size_t)p * 32 + bh) * 4096 + idx);
    u16x4 o;
#pragma unroll
    for (int j = 0; j < 4; ++j) o[j] = f2b(s[j]);
    *(u16x4*)(ctxb + (size_t)bh * 4096 + idx) = o;
  }
}

// ---------------------------------------------------------------------------
// out_fused: out[tileM..+128][tileN..+128] = (sum_h P_h @ Wo_h) + bo
// P_h computed as P^T = ctxb_h @ q'_h^T, routed through LDS (ps) to become
// the A-operand of the Wo MFMA. FIX vs R5: staging loop now covers all
// 128 rows (p < 4, 1024 chunks per array), not half.
// ---------------------------------------------------------------------------
__global__ void out_fused_kernel(const u16* __restrict__ qb, const u16* __restrict__ ctxb,
                                 const u16* __restrict__ Wot, const float* __restrict__ bias,
                                 float* __restrict__ out) {
  __shared__ u16 qs[128 * 64];   // 16 KB   q'_h tile
  __shared__ u16 ws[128 * 64];   // 16 KB   Wo_h slice (from Wot)
  __shared__ u16 ps[128 * 72];   // 18.4 KB P tile, row-major [n][e], stride 72
  const int id = blockIdx.x;
  const int tn = id >> 7;                            // 0..3
  const int tm = (id & 7) * 16 + ((id >> 3) & 15);   // 0..127
  const int tileN = tn * 128;
  const int rowBase = tm * 128;
  const int b = tm >> 5;
  const int t = threadIdx.x;
  const int lane = t & 63;
  const int wave = t >> 6;
  const int fm = lane & 15;
  const int kg = lane >> 4;
  const int rq = lane >> 4;
  const int mhalf = (wave >> 1) * 64;
  const int nhalf = (wave & 1) * 64;

  f32x4 oacc[4][4];
#pragma unroll
  for (int i = 0; i < 4; ++i)
#pragma unroll
    for (int j = 0; j < 4; ++j) oacc[i][j] = (f32x4){0.f, 0.f, 0.f, 0.f};

  for (int h = 0; h < 8; ++h) {
    // stage q'_h (128 rows x 64 d) and Wo_h slice (128 out-cols x 64 k):
    // 1024 8-elem chunks each -> p in [0,4)
#pragma unroll
    for (int p = 0; p < 4; ++p) {
      int idx = p * 256 + t;
      int row = idx >> 3;
      int slot = idx & 7;
      int g = slot ^ (row & 7);
      __builtin_amdgcn_global_load_lds(
          GLD_AS1(qb + (size_t)(rowBase + row) * 512 + h * 64 + g * 8),
          LDS_AS3(qs + idx * 8), 16, 0, 0);
      __builtin_amdgcn_global_load_lds(
          GLD_AS1(Wot + (size_t)(tileN + row) * 512 + h * 64 + g * 8),
          LDS_AS3(ws + idx * 8), 16, 0, 0);
    }
    __syncthreads();

    // P^T = ctxb_h (64e x 64d) @ q'_h^T : wave covers e-strip 32 x n-strip 64
    f32x4 pacc[2][4];
#pragma unroll
    for (int i = 0; i < 2; ++i)
#pragma unroll
      for (int j = 0; j < 4; ++j) pacc[i][j] = (f32x4){0.f, 0.f, 0.f, 0.f};
    const u16* cb = ctxb + (size_t)(b * 8 + h) * 4096;
#pragma unroll
    for (int ks = 0; ks < 2; ++ks) {
      bf16x8 af[2];
#pragma unroll
      for (int mi = 0; mi < 2; ++mi) {
        int e = (wave >> 1) * 32 + mi * 16 + fm;
        af[mi] = *(const bf16x8*)(cb + e * 64 + ks * 32 + kg * 8);
      }
#pragma unroll
      for (int ni = 0; ni < 4; ++ni) {
        int n = nhalf + ni * 16 + fm;
        int sl = (ks * 4 + kg) ^ (n & 7);
        bf16x8 bfq = *(const bf16x8*)(qs + n * 64 + sl * 8);
#pragma unroll
        for (int mi = 0; mi < 2; ++mi)
          pacc[mi][ni] = __builtin_amdgcn_mfma_f32_16x16x32_bf16(af[mi], bfq,
                                                                 pacc[mi][ni], 0, 0, 0);
      }
    }
    // write P (row-major [n][e], e-contig) — C-layout col=n, rows=e -> u16x4
#pragma unroll
    for (int mi = 0; mi < 2; ++mi)
#pragma unroll
      for (int ni = 0; ni < 4; ++ni) {
        u16x4 o;
#pragma unroll
        for (int reg = 0; reg < 4; ++reg) o[reg] = f2b(pacc[mi][ni][reg]);
        int n = nhalf + ni * 16 + fm;
        int e0 = (wave >> 1) * 32 + mi * 16 + rq * 4;
        *(u16x4*)(ps + n * 72 + e0) = o;
      }
    __syncthreads();

    // out-tile += P (128n x 64e) @ Wo_h (64e x 128c)
#pragma unroll
    for (int ks = 0; ks < 2; ++ks) {
      bf16x8 af2[4];
#pragma unroll
      for (int mi = 0; mi < 4; ++mi) {
        int m = mhalf + mi * 16 + fm;
        af2[mi] = *(const bf16x8*)(ps + m * 72 + ks * 32 + kg * 8);
      }
#pragma unroll
      for (int ni = 0; ni < 4; ++ni) {
        int n = nhalf + ni * 16 + fm;
        int sl = (ks * 4 + kg) ^ (n & 7);
        bf16x8 bfw = *(const bf16x8*)(ws + n * 64 + sl * 8);
#pragma unroll
        for (int mi = 0; mi < 4; ++mi)
          oacc[mi][ni] = __builtin_amdgcn_mfma_f32_16x16x32_bf16(af2[mi], bfw,
                                                                 oacc[mi][ni], 0, 0, 0);
      }
    }
    __syncthreads();  // protect qs/ws/ps before next h's staging
  }

#pragma unroll
  for (int mi = 0; mi < 4; ++mi)
#pragma unroll
    for (int ni = 0; ni < 4; ++ni)
#pragma unroll
      for (int reg = 0; reg < 4; ++reg) {
        int gr = rowBase + mhalf + mi * 16 + rq * 4 + reg;
        int gc = tileN + nhalf + ni * 16 + fm;
        out[(size_t)gr * 512 + gc] = oacc[mi][ni][reg] + bias[gc];
      }
}

// ---------------------------------------------------------------------------
extern "C" void kernel_launch(void* const* d_in, const int* in_sizes, int n_in,
                              void* d_out, int out_size, void* d_ws, size_t ws_size,
                              hipStream_t stream) {
  const float* x  = (const float*)d_in[0];
  const float* Wq = (const float*)d_in[1];
  const float* Wk = (const float*)d_in[2];
  const float* Wv = (const float*)d_in[3];
  const float* Wo = (const float*)d_in[4];
  const float* bo = (const float*)d_in[5];

  char* w = (char*)d_ws;
  u16* xb   = (u16*)w;    w += (size_t)16384 * 512 * 2;     // 16.8 MB
  u16* Wt   = (u16*)w;    w += (size_t)1536 * 512 * 2;      // 1.6 MB
  u16* Wot  = (u16*)w;    w += (size_t)512 * 512 * 2;       // 0.5 MB
  u16* qbuf = (u16*)w;    w += (size_t)16384 * 512 * 2;     // 16.8 MB
  u16* kT   = (u16*)w;    w += (size_t)32 * 64 * 4096 * 2;  // 16.8 MB
  u16* vT   = (u16*)w;    w += (size_t)32 * 64 * 4096 * 2;  // 16.8 MB
  float* ctxp = (float*)w; w += (size_t)16 * 32 * 4096 * 4; // 8.4 MB
  u16* ctxb = (u16*)w;    w += (size_t)32 * 4096 * 2;       // 0.26 MB

  prep_all_kernel<<<4352, 256, 0, stream>>>(x, Wq, Wk, Wv, Wo, xb, Wt, Wot);
  gemm_qkv_kernel<<<1536, 256, 0, stream>>>(xb, Wt, qbuf, kT, vT);
  context_kernel<<<dim3(32, 16), 256, 0, stream>>>(kT, vT, ctxp);
  ctx_reduce_kernel<<<32, 256, 0, stream>>>(ctxp, ctxb);
  out_fused_kernel<<<512, 256, 0, stream>>>(qbuf, ctxb, Wot, bo, (float*)d_out);
}

// Round 7
// 172.745 us; speedup vs baseline: 1.0601x; 1.0601x over previous
//
#include <hip/hip_runtime.h>

typedef unsigned short u16;
typedef unsigned int   u32;
typedef __bf16 bf16x8 __attribute__((ext_vector_type(8)));
typedef float  f32x4  __attribute__((ext_vector_type(4)));
typedef u16    u16x8  __attribute__((ext_vector_type(8)));
typedef u16    u16x4  __attribute__((ext_vector_type(4)));

__device__ __forceinline__ float b2f(u16 h) {
  return __builtin_bit_cast(float, ((u32)h) << 16);
}
__device__ __forceinline__ u16 f2b(float f) {
  u32 u = __builtin_bit_cast(u32, f);
  u32 r = u + 0x7FFFu + ((u >> 16) & 1u);
  return (u16)(r >> 16);
}

#define GLD_AS1(p) ((const __attribute__((address_space(1))) void*)(p))
#define LDS_AS3(p) ((__attribute__((address_space(3))) void*)(p))

// ---------------------------------------------------------------------------
// GEMM1 + fused softmax + transposed k/v stores. (unchanged, validated)
// ---------------------------------------------------------------------------
__global__ void gemm_qkv_kernel(const u16* __restrict__ A, const u16* __restrict__ Bt,
                                u16* __restrict__ qb, u16* __restrict__ kT,
                                u16* __restrict__ vT) {
  const int K = 512;
  __shared__ u16 smem[2 * 64 * 72];  // staging (16 KB) U transpose scratch
  u16* As = smem;
  u16* Bs = smem + 128 * 32;
  const int id = blockIdx.x;
  const int tn = id >> 7;
  const int tm = (id & 7) * 16 + ((id >> 3) & 15);
  const int tileN = tn * 128;
  const int tileM = tm * 128;
  const int t = threadIdx.x;
  const int lane = t & 63;
  const int wave = t >> 6;
  const int mbase = (wave >> 1) * 64;
  const int nbase = (wave & 1) * 64;
  const int fm = lane & 15;
  const int kg = lane >> 4;

  f32x4 acc[4][4];
#pragma unroll
  for (int i = 0; i < 4; ++i)
#pragma unroll
    for (int j = 0; j < 4; ++j) acc[i][j] = (f32x4){0.f, 0.f, 0.f, 0.f};

  for (int k0 = 0; k0 < K; k0 += 32) {
#pragma unroll
    for (int p = 0; p < 2; ++p) {
      int c = p * 256 + t;
      int r = c >> 2;
      int g = (c & 3) ^ ((r >> 1) & 3);
      const u16* ga = A + (size_t)(tileM + r) * K + (k0 + g * 8);
      __builtin_amdgcn_global_load_lds(GLD_AS1(ga), LDS_AS3(As + c * 8), 16, 0, 0);
      const u16* gb = Bt + (size_t)(tileN + r) * K + (k0 + g * 8);
      __builtin_amdgcn_global_load_lds(GLD_AS1(gb), LDS_AS3(Bs + c * 8), 16, 0, 0);
    }
    __syncthreads();

    bf16x8 af[4], bfr[4];
#pragma unroll
    for (int mi = 0; mi < 4; ++mi) {
      int m = mbase + mi * 16 + fm;
      int sg = kg ^ ((m >> 1) & 3);
      af[mi] = *(const bf16x8*)(As + m * 32 + sg * 8);
    }
#pragma unroll
    for (int ni = 0; ni < 4; ++ni) {
      int n = nbase + ni * 16 + fm;
      int sg = kg ^ ((n >> 1) & 3);
      bfr[ni] = *(const bf16x8*)(Bs + n * 32 + sg * 8);
    }
#pragma unroll
    for (int mi = 0; mi < 4; ++mi)
#pragma unroll
      for (int ni = 0; ni < 4; ++ni)
        acc[mi][ni] = __builtin_amdgcn_mfma_f32_16x16x32_bf16(af[mi], bfr[ni],
                                                              acc[mi][ni], 0, 0, 0);
    __syncthreads();
  }

  const int rq = lane >> 4;
  const int region = tn >> 2;  // 0 q, 1 k, 2 v

  float inv[4][4];
  if (region <= 1) {
#pragma unroll
    for (int mi = 0; mi < 4; ++mi)
#pragma unroll
      for (int ni = 0; ni < 4; ++ni)
#pragma unroll
        for (int reg = 0; reg < 4; ++reg)
          acc[mi][ni][reg] = __expf(acc[mi][ni][reg]);
#pragma unroll
    for (int mi = 0; mi < 4; ++mi)
#pragma unroll
      for (int reg = 0; reg < 4; ++reg) {
        float s = acc[mi][0][reg] + acc[mi][1][reg] + acc[mi][2][reg] + acc[mi][3][reg];
        s += __shfl_xor(s, 1);
        s += __shfl_xor(s, 2);
        s += __shfl_xor(s, 4);
        s += __shfl_xor(s, 8);
        inv[mi][reg] = 1.f / s;
      }
  } else {
#pragma unroll
    for (int mi = 0; mi < 4; ++mi)
#pragma unroll
      for (int reg = 0; reg < 4; ++reg) inv[mi][reg] = 1.f;
  }

  if (region == 0) {
#pragma unroll
    for (int mi = 0; mi < 4; ++mi)
#pragma unroll
      for (int ni = 0; ni < 4; ++ni)
#pragma unroll
        for (int reg = 0; reg < 4; ++reg) {
          int gr = tileM + mbase + mi * 16 + rq * 4 + reg;
          int gc = tileN + nbase + ni * 16 + fm;
          qb[(size_t)gr * 512 + gc] = f2b(acc[mi][ni][reg] * inv[mi][reg]);
        }
  }

  u16* scw = smem + (wave & 1) * (64 * 72);
  u16* base = (region == 1) ? kT : vT;
  const int hd = tileN + nbase - ((region == 1) ? 512 : 1024);
  const int gr0 = tileM + mbase;
  const int bh = (gr0 >> 12) * 8 + (hd >> 6);
  const int n0 = gr0 & 4095;

  auto transpose_store = [&]() {
#pragma unroll
    for (int mi = 0; mi < 4; ++mi)
#pragma unroll
      for (int ni = 0; ni < 4; ++ni) {
        u16x4 o;
#pragma unroll
        for (int reg = 0; reg < 4; ++reg)
          o[reg] = f2b(acc[mi][ni][reg] * inv[mi][reg]);
        *(u16x4*)(scw + (ni * 16 + fm) * 72 + mi * 16 + rq * 4) = o;
      }
#pragma unroll
    for (int i = 0; i < 8; ++i) {
      int row = i * 8 + (lane >> 3);
      int seg = lane & 7;
      u16x8 val = *(const u16x8*)(scw + row * 72 + seg * 8);
      *(u16x8*)(base + ((size_t)bh * 64 + row) * 4096 + n0 + seg * 8) = val;
    }
  };

  if (region != 0 && wave < 2) transpose_store();
  __syncthreads();
  if (region != 0 && wave >= 2) transpose_store();
}

// ---------------------------------------------------------------------------
// prep_all: [0,4096) cast x; [4096,4288) Wt tiles; [4288,4352) Wot tiles.
// ---------------------------------------------------------------------------
__global__ void prep_all_kernel(const float* __restrict__ x, const float* __restrict__ Wq,
                                const float* __restrict__ Wk, const float* __restrict__ Wv,
                                const float* __restrict__ Wo, u16* __restrict__ xb,
                                u16* __restrict__ Wt, u16* __restrict__ Wot) {
  __shared__ u16 tr[64 * 72];
  const int id = blockIdx.x;
  const int t = threadIdx.x;

  if (id < 4096) {
    int i = (id * 256 + t) * 8;
    float4 a = *(const float4*)(x + i);
    float4 b = *(const float4*)(x + i + 4);
    u16x8 o;
    o[0] = f2b(a.x); o[1] = f2b(a.y); o[2] = f2b(a.z); o[3] = f2b(a.w);
    o[4] = f2b(b.x); o[5] = f2b(b.y); o[6] = f2b(b.z); o[7] = f2b(b.w);
    *(u16x8*)(xb + i) = o;
    return;
  }
  const float* W;
  u16* dst;
  int n0, k0;
  if (id < 4288) {
    int tile = id - 4096;
    n0 = (tile >> 3) * 64;
    k0 = (tile & 7) * 64;
    W = (n0 < 512) ? Wq : ((n0 < 1024) ? Wk : Wv);
    dst = Wt;
  } else {
    int tile = id - 4288;
    n0 = (tile >> 3) * 64;
    k0 = (tile & 7) * 64;
    W = Wo;
    dst = Wot;
  }
  int cin = (n0 & 511);
  int c = t & 63;
  int r0 = t >> 6;
#pragma unroll
  for (int i = 0; i < 16; ++i) {
    int r = r0 * 16 + i;
    tr[c * 72 + r] = f2b(W[(size_t)(k0 + r) * 512 + cin + c]);
  }
  __syncthreads();
#pragma unroll
  for (int j = 0; j < 2; ++j) {
    int idx = j * 256 + t;
    int row = idx >> 3;
    int seg = idx & 7;
    u16x8 val = *(const u16x8*)(tr + row * 72 + seg * 8);
    *(u16x8*)(dst + (size_t)(n0 + row) * 512 + k0 + seg * 8) = val;
  }
}

// ---------------------------------------------------------------------------
// context partials, d-major: ctxp[s][bh][d][e] = sum over split's n of
// k'[n,d]*v[n,e]. (A-frag = kT rows d, B-frag = vT rows e.)
// ---------------------------------------------------------------------------
__global__ void context_kernel(const u16* __restrict__ kT, const u16* __restrict__ vT,
                               float* __restrict__ ctxp) {
  __shared__ u16 ks_lds[64 * 32];
  __shared__ u16 vs_lds[64 * 32];
  const int bh = blockIdx.x;
  const int s = blockIdx.y;
  const int t = threadIdx.x;
  const int lane = t & 63;
  const int wave = t >> 6;
  const int fm = lane & 15;
  const int kg = lane >> 4;

  const u16* kbase = kT + (size_t)bh * 64 * 4096;
  const u16* vbase = vT + (size_t)bh * 64 * 4096;
  const int r = t >> 2;
  const int slot = t & 3;
  const int g = slot ^ ((r >> 1) & 3);
  const size_t goff = (size_t)r * 4096 + s * 256 + g * 8;

  f32x4 acc[4];
#pragma unroll
  for (int i = 0; i < 4; ++i) acc[i] = (f32x4){0.f, 0.f, 0.f, 0.f};

  for (int ki = 0; ki < 8; ++ki) {
    __builtin_amdgcn_global_load_lds(GLD_AS1(vbase + goff + ki * 32),
                                     LDS_AS3(vs_lds + t * 8), 16, 0, 0);
    __builtin_amdgcn_global_load_lds(GLD_AS1(kbase + goff + ki * 32),
                                     LDS_AS3(ks_lds + t * 8), 16, 0, 0);
    __syncthreads();
    int d = wave * 16 + fm;
    bf16x8 af = *(const bf16x8*)(ks_lds + d * 32 + (kg ^ ((d >> 1) & 3)) * 8);
#pragma unroll
    for (int et = 0; et < 4; ++et) {
      int e = et * 16 + fm;
      bf16x8 bfr = *(const bf16x8*)(vs_lds + e * 32 + (kg ^ ((e >> 1) & 3)) * 8);
      acc[et] = __builtin_amdgcn_mfma_f32_16x16x32_bf16(af, bfr, acc[et], 0, 0, 0);
    }
    __syncthreads();
  }

  const int rq = lane >> 4;
  float* cp = ctxp + ((size_t)s * 32 + bh) * 4096;
#pragma unroll
  for (int et = 0; et < 4; ++et)
#pragma unroll
    for (int reg = 0; reg < 4; ++reg)
      cp[(wave * 16 + rq * 4 + reg) * 64 + et * 16 + fm] = acc[et][reg];
}

// ---------------------------------------------------------------------------
// ctxm: per (b,h): reduce 16 ctxp partials -> ctx_h (64d x 64e, bf16, LDS),
// then Mt[b][c][h*64+d] = sum_e Wot[c][h*64+e] * ctx_h[d][e]  (MFMA K=64,
// A = Wot rows c [global b128], B = ctx_h rows d [LDS, pad 72]).
// Grid 32, block 256: wave w owns c-range [w*128, w*128+128).
// ---------------------------------------------------------------------------
__global__ void ctxm_kernel(const float* __restrict__ ctxp, const u16* __restrict__ Wot,
                            u16* __restrict__ Mt) {
  __shared__ u16 ctxd[64 * 72];
  const int bh = blockIdx.x;
  const int b = bh >> 3, h = bh & 7;
  const int t = threadIdx.x;
  const int lane = t & 63;
  const int wave = t >> 6;
  const int fm = lane & 15;
  const int kg = lane >> 4;
  const int rq = lane >> 4;

#pragma unroll
  for (int it = 0; it < 4; ++it) {
    int idx = it * 1024 + t * 4;
    f32x4 s = (f32x4){0.f, 0.f, 0.f, 0.f};
#pragma unroll
    for (int p = 0; p < 16; ++p)
      s += *(const f32x4*)(ctxp + ((size_t)p * 32 + bh) * 4096 + idx);
    u16x4 o;
#pragma unroll
    for (int j = 0; j < 4; ++j) o[j] = f2b(s[j]);
    int d = idx >> 6, e = idx & 63;
    *(u16x4*)(ctxd + d * 72 + e) = o;
  }
  __syncthreads();

  f32x4 acc[8][4];
#pragma unroll
  for (int i = 0; i < 8; ++i)
#pragma unroll
    for (int j = 0; j < 4; ++j) acc[i][j] = (f32x4){0.f, 0.f, 0.f, 0.f};

#pragma unroll
  for (int ks = 0; ks < 2; ++ks) {
    bf16x8 bfr[4];
#pragma unroll
    for (int dt = 0; dt < 4; ++dt)
      bfr[dt] = *(const bf16x8*)(ctxd + (dt * 16 + fm) * 72 + ks * 32 + kg * 8);
#pragma unroll
    for (int mi = 0; mi < 8; ++mi) {
      int c = wave * 128 + mi * 16 + fm;
      bf16x8 af = *(const bf16x8*)(Wot + (size_t)c * 512 + h * 64 + ks * 32 + kg * 8);
#pragma unroll
      for (int dt = 0; dt < 4; ++dt)
        acc[mi][dt] = __builtin_amdgcn_mfma_f32_16x16x32_bf16(af, bfr[dt],
                                                              acc[mi][dt], 0, 0, 0);
    }
  }

  u16* mb = Mt + (size_t)b * 512 * 512;
#pragma unroll
  for (int mi = 0; mi < 8; ++mi)
#pragma unroll
    for (int dt = 0; dt < 4; ++dt)
#pragma unroll
      for (int reg = 0; reg < 4; ++reg) {
        int c = wave * 128 + mi * 16 + rq * 4 + reg;
        mb[(size_t)c * 512 + h * 64 + dt * 16 + fm] = f2b(acc[mi][dt][reg]);
      }
}

// ---------------------------------------------------------------------------
// Final GEMM: out[b] = q'[b] @ Mt[b]^T + bo  (batched over b via tileM).
// 128-tile proven structure, XCD-swizzled 1-D grid 512.
// ---------------------------------------------------------------------------
__global__ void gemm_out_kernel(const u16* __restrict__ A, const u16* __restrict__ Mt,
                                float* __restrict__ Cout, const float* __restrict__ bias) {
  const int K = 512, N = 512;
  __shared__ u16 As[128 * 32];
  __shared__ u16 Bs[128 * 32];
  const int id = blockIdx.x;
  const int tn = id >> 7;
  const int tm = (id & 7) * 16 + ((id >> 3) & 15);
  const int tileN = tn * 128;
  const int tileM = tm * 128;
  const u16* Bt = Mt + (size_t)(tm >> 5) * 512 * 512;
  const int t = threadIdx.x;
  const int lane = t & 63;
  const int wave = t >> 6;
  const int mbase = (wave >> 1) * 64;
  const int nbase = (wave & 1) * 64;
  const int fm = lane & 15;
  const int kg = lane >> 4;

  f32x4 acc[4][4];
#pragma unroll
  for (int i = 0; i < 4; ++i)
#pragma unroll
    for (int j = 0; j < 4; ++j) acc[i][j] = (f32x4){0.f, 0.f, 0.f, 0.f};

  for (int k0 = 0; k0 < K; k0 += 32) {
#pragma unroll
    for (int p = 0; p < 2; ++p) {
      int c = p * 256 + t;
      int r = c >> 2;
      int g = (c & 3) ^ ((r >> 1) & 3);
      const u16* ga = A + (size_t)(tileM + r) * K + (k0 + g * 8);
      __builtin_amdgcn_global_load_lds(GLD_AS1(ga), LDS_AS3(As + c * 8), 16, 0, 0);
      const u16* gb = Bt + (size_t)(tileN + r) * K + (k0 + g * 8);
      __builtin_amdgcn_global_load_lds(GLD_AS1(gb), LDS_AS3(Bs + c * 8), 16, 0, 0);
    }
    __syncthreads();

    bf16x8 af[4], bfr[4];
#pragma unroll
    for (int mi = 0; mi < 4; ++mi) {
      int m = mbase + mi * 16 + fm;
      int sg = kg ^ ((m >> 1) & 3);
      af[mi] = *(const bf16x8*)(As + m * 32 + sg * 8);
    }
#pragma unroll
    for (int ni = 0; ni < 4; ++ni) {
      int n = nbase + ni * 16 + fm;
      int sg = kg ^ ((n >> 1) & 3);
      bfr[ni] = *(const bf16x8*)(Bs + n * 32 + sg * 8);
    }
#pragma unroll
    for (int mi = 0; mi < 4; ++mi)
#pragma unroll
      for (int ni = 0; ni < 4; ++ni)
        acc[mi][ni] = __builtin_amdgcn_mfma_f32_16x16x32_bf16(af[mi], bfr[ni],
                                                              acc[mi][ni], 0, 0, 0);
    __syncthreads();
  }

  const int rq = lane >> 4;
#pragma unroll
  for (int mi = 0; mi < 4; ++mi)
#pragma unroll
    for (int ni = 0; ni < 4; ++ni)
#pragma unroll
      for (int reg = 0; reg < 4; ++reg) {
        int gr = tileM + mbase + mi * 16 + rq * 4 + reg;
        int gc = tileN + nbase + ni * 16 + fm;
        Cout[(size_t)gr * N + gc] = acc[mi][ni][reg] + bias[gc];
      }
}

// ---------------------------------------------------------------------------
extern "C" void kernel_launch(void* const* d_in, const int* in_sizes, int n_in,
                              void* d_out, int out_size, void* d_ws, size_t ws_size,
                              hipStream_t stream) {
  const float* x  = (const float*)d_in[0];
  const float* Wq = (const float*)d_in[1];
  const float* Wk = (const float*)d_in[2];
  const float* Wv = (const float*)d_in[3];
  const float* Wo = (const float*)d_in[4];
  const float* bo = (const float*)d_in[5];

  char* w = (char*)d_ws;
  u16* xb   = (u16*)w;    w += (size_t)16384 * 512 * 2;     // 16.8 MB
  u16* Wt   = (u16*)w;    w += (size_t)1536 * 512 * 2;      // 1.6 MB
  u16* Wot  = (u16*)w;    w += (size_t)512 * 512 * 2;       // 0.5 MB
  u16* qbuf = (u16*)w;    w += (size_t)16384 * 512 * 2;     // 16.8 MB
  u16* kT   = (u16*)w;    w += (size_t)32 * 64 * 4096 * 2;  // 16.8 MB
  u16* vT   = (u16*)w;    w += (size_t)32 * 64 * 4096 * 2;  // 16.8 MB
  float* ctxp = (float*)w; w += (size_t)16 * 32 * 4096 * 4; // 8.4 MB
  u16* Mt   = (u16*)w;    w += (size_t)4 * 512 * 512 * 2;   // 2.1 MB

  prep_all_kernel<<<4352, 256, 0, stream>>>(x, Wq, Wk, Wv, Wo, xb, Wt, Wot);
  gemm_qkv_kernel<<<1536, 256, 0, stream>>>(xb, Wt, qbuf, kT, vT);
  context_kernel<<<dim3(32, 16), 256, 0, stream>>>(kT, vT, ctxp);
  ctxm_kernel<<<32, 256, 0, stream>>>(ctxp, Wot, Mt);
  gemm_out_kernel<<<512, 256, 0, stream>>>(qbuf, Mt, (float*)d_out, bo);
}